// Round 1
// baseline (128.184 us; speedup 1.0000x reference)
//
#include <hip/hip_runtime.h>
#include <hip/hip_bf16.h>
#include <stdint.h>

typedef short bf16x8 __attribute__((ext_vector_type(8)));
typedef float f32x4 __attribute__((ext_vector_type(4)));

#define DEVI static __device__ __forceinline__

constexpr int B_   = 32768;
constexpr int IN_  = 128;
constexpr int LF_  = 512;
constexpr int OUT_ = 32;
constexpr int NE_  = 48;   // padded N for pi GEMM: 32 pi + 1 qb + 15 zero

// ---- workspace layout (bytes) ----
constexpr size_t OFF_XB  = 0;                        // 32768*128*2  = 8,388,608
constexpr size_t OFF_PHI = 8388608;                  // 32768*512*2  = 33,554,432
constexpr size_t OFF_LT  = OFF_PHI + 33554432;       // 512*512*2    = 524,288
constexpr size_t OFF_W1  = OFF_LT + 524288;          // 512*128*2    = 131,072
constexpr size_t OFF_W2E = OFF_W1 + 131072;          // 48*512*2     = 49,152

// ---- async global->LDS, 16B per lane, dest = wave-uniform base + lane*16 ----
DEVI void gl2lds16(const void* g, void* l) {
    __builtin_amdgcn_global_load_lds(
        (const __attribute__((address_space(1))) unsigned int*)g,
        (__attribute__((address_space(3))) unsigned int*)l,
        16, 0, 0);
}

// Stage a 128-row x 64-col bf16 tile (row-major src, ld elems/row) into LDS.
// LDS layout: 1024 16B chunks; chunk for (row, global-chunk c) lives at slot
// row*8 + (c ^ (row&7)).  The XOR swizzle is applied on the GLOBAL fetch side
// so global_load_lds (which scatters lane i -> base + i*16) still works, and
// fragment ds_read_b128s land 2-way on banks (free).
DEVI void stage128x64(const __hip_bfloat16* src, int ld, char* lds, int tid) {
    int wv = tid >> 6;
    char* base = lds + (size_t)(wv * 64) * 16;
#pragma unroll
    for (int it = 0; it < 4; ++it) {
        int slot = it * 256 + tid;          // 0..1023
        int row  = slot >> 3;
        int c    = (slot & 7) ^ (row & 7);  // global chunk for this LDS slot
        gl2lds16(src + (size_t)row * ld + c * 8, base + it * 256 * 16);
    }
}

// Read an 8-bf16 fragment (row, k-offset within 64-wide tile) from swizzled LDS.
DEVI bf16x8 fragLD(const char* lds, int row, int kofs) {
    int c    = kofs >> 3;
    int slot = row * 8 + ((c ^ (row & 7)));
    return *(const bf16x8*)(lds + (size_t)slot * 16);
}

// ---------------- prep: casts + Lt unpack + W2ext build ----------------
__global__ __launch_bounds__(256) void k_prep(
        const float* __restrict__ x,  const float* __restrict__ w1,
        const float* __restrict__ w2, const float* __restrict__ lv,
        const float* __restrict__ qb,
        __hip_bfloat16* __restrict__ xb, __hip_bfloat16* __restrict__ w1b,
        __hip_bfloat16* __restrict__ lt, __hip_bfloat16* __restrict__ w2e) {
    int gt = blockIdx.x * blockDim.x + threadIdx.x;
    int st = gridDim.x * blockDim.x;
    for (int i = gt; i < B_ * IN_; i += st) xb[i] = __float2bfloat16(x[i]);
    for (int i = gt; i < LF_ * IN_; i += st) w1b[i] = __float2bfloat16(w1[i]);
    for (int i = gt; i < NE_ * LF_; i += st) {
        int n = i >> 9, k = i & 511;
        float v = (n < OUT_) ? w2[n * LF_ + k] : (n == OUT_ ? qb[k] : 0.f);
        w2e[i] = __float2bfloat16(v);
    }
    for (int i = gt; i < LF_ * LF_; i += st) {
        int j = i >> 9, k = i & 511;  // Lt[j][k] = L[k][j], lower-tri: k >= j
        float v = (k >= j) ? lv[k * (k + 1) / 2 + j] : 0.f;
        lt[i] = __float2bfloat16(v);
    }
}

// ---------------- phi = tanh(x @ W1^T + b1), bf16 out ----------------
__global__ __launch_bounds__(256) void k_phi(
        const __hip_bfloat16* __restrict__ xb, const __hip_bfloat16* __restrict__ w1,
        const float* __restrict__ b1, __hip_bfloat16* __restrict__ phi) {
    __shared__ char As[16384];
    __shared__ char Bs[16384];
    int tid = threadIdx.x;
    int m0 = blockIdx.x * 128, n0 = blockIdx.y * 128;
    int wv = tid >> 6, ln = tid & 63;
    int wm = (wv & 1) * 64, wn = (wv >> 1) * 64;
    int cl = ln & 15, q = ln >> 4;
    f32x4 acc[4][4] = {};
    for (int k0 = 0; k0 < IN_; k0 += 64) {
        stage128x64(xb + (size_t)m0 * IN_ + k0, IN_, As, tid);
        stage128x64(w1 + (size_t)n0 * IN_ + k0, IN_, Bs, tid);
        __syncthreads();
#pragma unroll
        for (int kk = 0; kk < 64; kk += 32) {
            bf16x8 af[4], bf[4];
#pragma unroll
            for (int i = 0; i < 4; ++i) af[i] = fragLD(As, wm + i * 16 + cl, kk + q * 8);
#pragma unroll
            for (int i = 0; i < 4; ++i) bf[i] = fragLD(Bs, wn + i * 16 + cl, kk + q * 8);
#pragma unroll
            for (int mi = 0; mi < 4; ++mi)
#pragma unroll
                for (int ni = 0; ni < 4; ++ni)
                    acc[mi][ni] = __builtin_amdgcn_mfma_f32_16x16x32_bf16(
                        af[mi], bf[ni], acc[mi][ni], 0, 0, 0);
        }
        __syncthreads();
    }
    // epilogue: tanh(acc + b1) -> bf16 phi.  C/D: col=lane&15, row=quad*4+r.
#pragma unroll
    for (int ni = 0; ni < 4; ++ni) {
        int col = n0 + wn + ni * 16 + cl;
        float bv = b1[col];
#pragma unroll
        for (int mi = 0; mi < 4; ++mi)
#pragma unroll
            for (int r = 0; r < 4; ++r) {
                int row = m0 + wm + mi * 16 + q * 4 + r;
                phi[(size_t)row * LF_ + col] = __float2bfloat16(tanhf(acc[mi][ni][r] + bv));
            }
    }
}

// ---------------- pi = phi @ W2ext^T ; vf init = phi.qb + qc ----------------
__global__ __launch_bounds__(256) void k_pi(
        const __hip_bfloat16* __restrict__ phi, const __hip_bfloat16* __restrict__ w2e,
        const float* __restrict__ qcp, float* __restrict__ pi, float* __restrict__ vf) {
    __shared__ char As[16384];
    __shared__ char Bs[49152];  // full W2ext: 48 rows x 64 chunks x 16B, swizzled
    int tid = threadIdx.x;
    int m0 = blockIdx.x * 128;
    int wv = tid >> 6, ln = tid & 63;
    int cl = ln & 15, q = ln >> 4;
    {   // stage all of W2ext once: 3072 slots
        char* base = Bs + (size_t)(wv * 64) * 16;
#pragma unroll
        for (int it = 0; it < 12; ++it) {
            int slot = it * 256 + tid;
            int n = slot >> 6;
            int c = (slot & 63) ^ (n & 7);
            gl2lds16(w2e + (size_t)n * LF_ + c * 8, base + it * 256 * 16);
        }
    }
    f32x4 acc[2][3] = {};
    for (int k0 = 0; k0 < LF_; k0 += 64) {
        stage128x64(phi + (size_t)m0 * LF_ + k0, LF_, As, tid);
        __syncthreads();
#pragma unroll
        for (int kk = 0; kk < 64; kk += 32) {
            bf16x8 af[2], bf[3];
#pragma unroll
            for (int i = 0; i < 2; ++i) af[i] = fragLD(As, wv * 32 + i * 16 + cl, kk + q * 8);
#pragma unroll
            for (int i = 0; i < 3; ++i) {
                int n = i * 16 + cl;
                int C = (k0 + kk) / 8 + q;         // chunk index in full 512-wide row
                int slot = n * 64 + (C ^ (n & 7));
                bf[i] = *(const bf16x8*)(Bs + (size_t)slot * 16);
            }
#pragma unroll
            for (int mi = 0; mi < 2; ++mi)
#pragma unroll
                for (int ni = 0; ni < 3; ++ni)
                    acc[mi][ni] = __builtin_amdgcn_mfma_f32_16x16x32_bf16(
                        af[mi], bf[ni], acc[mi][ni], 0, 0, 0);
        }
        __syncthreads();
    }
    float qc0 = qcp[0];
#pragma unroll
    for (int mi = 0; mi < 2; ++mi)
#pragma unroll
        for (int r = 0; r < 4; ++r) {
            int row = m0 + wv * 32 + mi * 16 + q * 4 + r;
#pragma unroll
            for (int ni = 0; ni < 3; ++ni) {
                float v = acc[mi][ni][r];
                int col = ni * 16 + cl;
                if (col < OUT_)      pi[(size_t)row * OUT_ + col] = v;
                else if (col == OUT_) vf[row] = v + qc0;  // phi.qb + qc
            }
        }
}

// ---------------- y += rowsum( (phi @ L)^2 )  [triangular K-skip] ----------------
__global__ __launch_bounds__(256) void k_y(
        const __hip_bfloat16* __restrict__ phi, const __hip_bfloat16* __restrict__ lt,
        float* __restrict__ vf) {
    __shared__ char As[16384];
    __shared__ char Bs[16384];
    int tid = threadIdx.x;
    int m0 = blockIdx.x * 128, n0 = blockIdx.y * 128;
    int wv = tid >> 6, ln = tid & 63;
    int wm = (wv & 1) * 64, wn = (wv >> 1) * 64;
    int cl = ln & 15, q = ln >> 4;
    f32x4 acc[4][4] = {};
    // Lt[j][k] == 0 for k < j, so for columns [n0, n0+128) only k >= n0 matters.
    for (int k0 = n0; k0 < LF_; k0 += 64) {
        stage128x64(phi + (size_t)m0 * LF_ + k0, LF_, As, tid);
        stage128x64(lt  + (size_t)n0 * LF_ + k0, LF_, Bs, tid);
        __syncthreads();
#pragma unroll
        for (int kk = 0; kk < 64; kk += 32) {
            bf16x8 af[4], bf[4];
#pragma unroll
            for (int i = 0; i < 4; ++i) af[i] = fragLD(As, wm + i * 16 + cl, kk + q * 8);
#pragma unroll
            for (int i = 0; i < 4; ++i) bf[i] = fragLD(Bs, wn + i * 16 + cl, kk + q * 8);
#pragma unroll
            for (int mi = 0; mi < 4; ++mi)
#pragma unroll
                for (int ni = 0; ni < 4; ++ni)
                    acc[mi][ni] = __builtin_amdgcn_mfma_f32_16x16x32_bf16(
                        af[mi], bf[ni], acc[mi][ni], 0, 0, 0);
        }
        __syncthreads();
    }
    // epilogue: v = sum over this wave's 64 cols of u^2, per row; butterfly over
    // the 16 col-lanes (bits 0-3), then one atomicAdd per row from col-lane 0.
#pragma unroll
    for (int mi = 0; mi < 4; ++mi)
#pragma unroll
        for (int r = 0; r < 4; ++r) {
            float v = 0.f;
#pragma unroll
            for (int ni = 0; ni < 4; ++ni) { float t = acc[mi][ni][r]; v += t * t; }
            v += __shfl_xor(v, 1, 64);
            v += __shfl_xor(v, 2, 64);
            v += __shfl_xor(v, 4, 64);
            v += __shfl_xor(v, 8, 64);
            if (cl == 0) atomicAdd(&vf[m0 + wm + mi * 16 + q * 4 + r], v);
        }
}

extern "C" void kernel_launch(void* const* d_in, const int* in_sizes, int n_in,
                              void* d_out, int out_size, void* d_ws, size_t ws_size,
                              hipStream_t stream) {
    const float* x  = (const float*)d_in[0];
    const float* w1 = (const float*)d_in[1];
    const float* b1 = (const float*)d_in[2];
    const float* w2 = (const float*)d_in[3];
    const float* lv = (const float*)d_in[4];
    const float* qb = (const float*)d_in[5];
    const float* qc = (const float*)d_in[6];

    char* ws = (char*)d_ws;
    __hip_bfloat16* xb  = (__hip_bfloat16*)(ws + OFF_XB);
    __hip_bfloat16* phi = (__hip_bfloat16*)(ws + OFF_PHI);
    __hip_bfloat16* lt  = (__hip_bfloat16*)(ws + OFF_LT);
    __hip_bfloat16* w1b = (__hip_bfloat16*)(ws + OFF_W1);
    __hip_bfloat16* w2e = (__hip_bfloat16*)(ws + OFF_W2E);

    float* pi = (float*)d_out;
    float* vf = pi + (size_t)B_ * OUT_;

    k_prep<<<1024, 256, 0, stream>>>(x, w1, w2, lv, qb, xb, w1b, lt, w2e);
    k_phi<<<dim3(B_ / 128, LF_ / 128), 256, 0, stream>>>(xb, w1b, b1, phi);
    k_pi <<<B_ / 128, 256, 0, stream>>>(phi, w2e, qc, pi, vf);
    k_y  <<<dim3(B_ / 128, LF_ / 128), 256, 0, stream>>>(phi, lt, vf);
}